// Round 1
// baseline (16.785 us; speedup 1.0000x reference)
//
#include <hip/hip_runtime.h>

// Problem constants (from reference)
#define NTRAJ 64
#define TSTEP 64
#define DFEAT 256
#define NT    (NTRAJ * TSTEP)   // 4096
#define MROWS (2 * NT)          // 8192

// Derived mask sums (exact integers):
//   sum(pos_w) = 64 * 128^2 - 8192        = 1,040,384
//   sum(neg_w) = 8192^2 - 64 * 128^2      = 66,060,288
#define POS_DEN 1040384.0
#define NEG_DEN 66060288.0

// K1: one block per trajectory group g (0..63). The group's 128 rows are
// z[g*64 .. g*64+63] and z[4096+g*64 .. 4096+g*64+63].
// Block = 256 threads = 4 waves; each wave handles 32 rows; each lane loads
// float4 (4 contiguous floats) of the 256-wide row. Per row: wave-reduce
// sum-of-squares, normalize, accumulate into per-lane register partials of
// the group sum-vector S_g, plus the diagonal term |zn_i|^2 = ss * rinv^2.
__global__ __launch_bounds__(256)
void tsl_group_kernel(const float* __restrict__ z,
                      float* __restrict__ St,    // [64][256] group sum vectors
                      float* __restrict__ diag)  // [64] per-group sum |zn_i|^2
{
    const int g    = blockIdx.x;     // 0..63
    const int tid  = threadIdx.x;    // 0..255
    const int w    = tid >> 6;       // wave 0..3
    const int lane = tid & 63;       // 0..63

    float a0 = 0.f, a1 = 0.f, a2 = 0.f, a3 = 0.f;
    float dpart = 0.f;

    #pragma unroll 4
    for (int r = 0; r < 32; ++r) {
        const int m   = w * 32 + r;                                   // 0..127 within group
        const int row = (m < 64) ? (g * 64 + m) : (NT + g * 64 + (m - 64));
        const float4 v = *reinterpret_cast<const float4*>(
            z + (size_t)row * DFEAT + (size_t)lane * 4);

        float ss = v.x * v.x + v.y * v.y + v.z * v.z + v.w * v.w;
        // full-wave (64-lane) butterfly reduction
        #pragma unroll
        for (int off = 32; off > 0; off >>= 1)
            ss += __shfl_xor(ss, off, 64);

        const float rinv = 1.0f / fmaxf(sqrtf(ss), 1e-8f);
        a0 += v.x * rinv;
        a1 += v.y * rinv;
        a2 += v.z * rinv;
        a3 += v.w * rinv;
        if (lane == 0) dpart += ss * rinv * rinv;   // |zn_row|^2
    }

    // Combine the 4 waves' partials into S_g.
    __shared__ float4 S4[4][64];     // viewed as float[4][256]
    __shared__ float dd[4];
    S4[w][lane] = make_float4(a0, a1, a2, a3);
    if (lane == 0) dd[w] = dpart;
    __syncthreads();

    const float* Sf = reinterpret_cast<const float*>(S4);
    const float s = Sf[0 * 256 + tid] + Sf[1 * 256 + tid] +
                    Sf[2 * 256 + tid] + Sf[3 * 256 + tid];
    St[g * 256 + tid] = s;
    if (tid == 0) diag[g] = dd[0] + dd[1] + dd[2] + dd[3];
}

// K2: single block. G1 = sum_g |S_g|^2, G2 = |sum_g S_g|^2, DG = sum diag.
// positive_sim = (G1 - DG) / POS_DEN ; negative_sim = (G2 - G1) / NEG_DEN.
__global__ __launch_bounds__(256)
void tsl_final_kernel(const float* __restrict__ St,
                      const float* __restrict__ diag,
                      float* __restrict__ out)
{
    const int tid = threadIdx.x;   // 0..255 = feature column

    double g1 = 0.0, col = 0.0;
    #pragma unroll 8
    for (int g = 0; g < 64; ++g) {
        const float v = St[g * 256 + tid];
        g1  += (double)v * (double)v;
        col += (double)v;
    }
    const double g2 = col * col;
    const double dg = (tid < 64) ? (double)diag[tid] : 0.0;

    __shared__ double r1[256], r2[256], r3[256];
    r1[tid] = g1; r2[tid] = g2; r3[tid] = dg;
    __syncthreads();
    #pragma unroll
    for (int s = 128; s > 0; s >>= 1) {
        if (tid < s) {
            r1[tid] += r1[tid + s];
            r2[tid] += r2[tid + s];
            r3[tid] += r3[tid + s];
        }
        __syncthreads();
    }

    if (tid == 0) {
        const double G1 = r1[0], G2 = r2[0], DG = r3[0];
        out[0] = (float)((G1 - DG) / POS_DEN);   // positive_sim
        out[1] = (float)((G2 - G1) / NEG_DEN);   // negative_sim
    }
}

extern "C" void kernel_launch(void* const* d_in, const int* in_sizes, int n_in,
                              void* d_out, int out_size, void* d_ws, size_t ws_size,
                              hipStream_t stream) {
    const float* z = (const float*)d_in[0];
    // d_in[1] (done) is provably unused: dm carries a tm factor, so
    // (1-dm)(1-tm) == (1-tm) identically.
    float* St   = (float*)d_ws;                                    // 64*256 floats
    float* diag = (float*)((char*)d_ws + 64 * 256 * sizeof(float)); // 64 floats
    float* out  = (float*)d_out;

    tsl_group_kernel<<<64, 256, 0, stream>>>(z, St, diag);
    tsl_final_kernel<<<1, 256, 0, stream>>>(St, diag, out);
}

// Round 2
// 15.932 us; speedup vs baseline: 1.0535x; 1.0535x over previous
//
#include <hip/hip_runtime.h>

// Problem constants (from reference)
#define NTRAJ 64
#define TSTEP 64
#define DFEAT 256
#define NT    (NTRAJ * TSTEP)   // 4096
#define MROWS (2 * NT)          // 8192

// Derived mask sums (exact integers):
//   sum(pos_w) = 64 * 128^2 - 8192        = 1,040,384
//   sum(neg_w) = 8192^2 - 64 * 128^2      = 66,060,288
#define POS_DEN 1040384.0
#define NEG_DEN 66060288.0

// Identity used: positive_mask = 1 - tm + eye (done cancels: dm carries a tm
// factor, so (1-dm)(1-tm) == (1-tm)). Then with zn = row-normalized z,
//   pos_sum = sum_g |S_g|^2 - sum_i |zn_i|^2,  S_g = sum of group-g rows of zn
//   neg_sum = |sum_i zn_i|^2 - sum_g |S_g|^2
// Group g (0..63) rows: [g*64, g*64+64) and [4096+g*64, 4096+g*64+64).

// K1: 256 blocks x 512 threads. Block b handles 32 consecutive flat rows
// [32b, 32b+32) — always within a single group's half (32 | 64).
// 8 waves/block, 4 rows/wave; per row: float4 load (16B/lane, coalesced),
// 6-step butterfly sum-of-squares, normalize, accumulate per-lane partials.
__global__ __launch_bounds__(512)
void tsl_partial_kernel(const float* __restrict__ z,
                        float* __restrict__ P,    // [256][256] partial sums
                        float* __restrict__ Dp)   // [256] partial diag sums
{
    const int b    = blockIdx.x;     // 0..255
    const int tid  = threadIdx.x;    // 0..511
    const int w    = tid >> 6;       // wave 0..7
    const int lane = tid & 63;       // 0..63

    float a0 = 0.f, a1 = 0.f, a2 = 0.f, a3 = 0.f;
    float dpart = 0.f;

    #pragma unroll
    for (int r = 0; r < 4; ++r) {
        const int row = b * 32 + w * 4 + r;
        const float4 v = *reinterpret_cast<const float4*>(
            z + (size_t)row * DFEAT + (size_t)lane * 4);

        float ss = v.x * v.x + v.y * v.y + v.z * v.z + v.w * v.w;
        #pragma unroll
        for (int off = 32; off > 0; off >>= 1)
            ss += __shfl_xor(ss, off, 64);

        const float rinv = 1.0f / fmaxf(sqrtf(ss), 1e-8f);
        a0 += v.x * rinv;
        a1 += v.y * rinv;
        a2 += v.z * rinv;
        a3 += v.w * rinv;
        if (lane == 0) dpart += ss * rinv * rinv;   // |zn_row|^2
    }

    __shared__ float S[8][256];
    __shared__ float dd[8];
    *reinterpret_cast<float4*>(&S[w][lane * 4]) = make_float4(a0, a1, a2, a3);
    if (lane == 0) dd[w] = dpart;
    __syncthreads();

    if (tid < 256) {
        float s = 0.f;
        #pragma unroll
        for (int k = 0; k < 8; ++k) s += S[k][tid];
        P[b * 256 + tid] = s;
        if (tid == 0) {
            float d = 0.f;
            #pragma unroll
            for (int k = 0; k < 8; ++k) d += dd[k];
            Dp[b] = d;
        }
    }
}

// K2: single block, 256 threads (thread = feature column).
// Group g's partials are blocks {2g, 2g+1, 128+2g, 128+2g+1}.
__global__ __launch_bounds__(256)
void tsl_final_kernel(const float* __restrict__ P,
                      const float* __restrict__ Dp,
                      float* __restrict__ out)
{
    const int tid  = threadIdx.x;   // 0..255
    const int w    = tid >> 6;
    const int lane = tid & 63;

    double g1 = 0.0, col = 0.0;
    #pragma unroll 8
    for (int g = 0; g < 64; ++g) {
        const float s = P[(2 * g) * 256 + tid] + P[(2 * g + 1) * 256 + tid] +
                        P[(128 + 2 * g) * 256 + tid] + P[(129 + 2 * g) * 256 + tid];
        g1  += (double)s * (double)s;
        col += (double)s;
    }
    double g2 = col * col;
    double dg = (double)Dp[tid];

    // 64-lane wave reduce, then combine the 4 waves through LDS.
    #pragma unroll
    for (int off = 32; off > 0; off >>= 1) {
        g1 += __shfl_down(g1, off, 64);
        g2 += __shfl_down(g2, off, 64);
        dg += __shfl_down(dg, off, 64);
    }
    __shared__ double W[3][4];
    if (lane == 0) { W[0][w] = g1; W[1][w] = g2; W[2][w] = dg; }
    __syncthreads();

    if (tid == 0) {
        const double G1 = W[0][0] + W[0][1] + W[0][2] + W[0][3];
        const double G2 = W[1][0] + W[1][1] + W[1][2] + W[1][3];
        const double DG = W[2][0] + W[2][1] + W[2][2] + W[2][3];
        out[0] = (float)((G1 - DG) / POS_DEN);   // positive_sim
        out[1] = (float)((G2 - G1) / NEG_DEN);   // negative_sim
    }
}

extern "C" void kernel_launch(void* const* d_in, const int* in_sizes, int n_in,
                              void* d_out, int out_size, void* d_ws, size_t ws_size,
                              hipStream_t stream) {
    const float* z = (const float*)d_in[0];
    // d_in[1] (done) provably unused: (1-dm)(1-tm) == (1-tm).
    float* P   = (float*)d_ws;                                      // 256*256 floats
    float* Dp  = (float*)((char*)d_ws + 256 * 256 * sizeof(float)); // 256 floats
    float* out = (float*)d_out;

    tsl_partial_kernel<<<256, 512, 0, stream>>>(z, P, Dp);
    tsl_final_kernel<<<1, 256, 0, stream>>>(P, Dp, out);
}